// Round 20
// baseline (157.452 us; speedup 1.0000x reference)
//
#include <hip/hip_runtime.h>
#include <hip/hip_bf16.h>

typedef unsigned short u16;
typedef __attribute__((ext_vector_type(8))) short short8;
typedef __attribute__((ext_vector_type(4))) float f32x4;
typedef __attribute__((ext_vector_type(4))) unsigned short us4;
typedef __attribute__((ext_vector_type(8))) _Float16 h8;

__device__ __forceinline__ u16 f32_bf16(float f) {
  union { float f; unsigned int u; } v; v.f = f;
  unsigned int r = v.u + 0x7fffu + ((v.u >> 16) & 1u);  // round-to-nearest-even
  return (u16)(r >> 16);
}
__device__ __forceinline__ float bf16_f32(u16 h) {
  union { unsigned int u; float f; } v; v.u = ((unsigned int)h) << 16; return v.f;
}
__device__ __forceinline__ u16 f32_f16(float f) {
  union { _Float16 h; u16 u; } v; v.h = (_Float16)f; return v.u;
}
__device__ __forceinline__ h8 splat8(float f) {
  _Float16 h = (_Float16)f;
  h8 r = {h, h, h, h, h, h, h, h};
  return r;
}
__device__ __forceinline__ unsigned long long pack4bf(float4 v) {
  return (unsigned long long)f32_bf16(v.x)
       | ((unsigned long long)f32_bf16(v.y) << 16)
       | ((unsigned long long)f32_bf16(v.z) << 32)
       | ((unsigned long long)f32_bf16(v.w) << 48);
}

__device__ __forceinline__ void load_lds16(const void* g, void* l) {
  __builtin_amdgcn_global_load_lds((const __attribute__((address_space(1))) unsigned int*)g,
                                   (__attribute__((address_space(3))) unsigned int*)l,
                                   16, 0, 0);
}

// ------- feature transpose ONLY (1344 blocks) ---------------------------------
// Async-staged: 16 outstanding 1KB channel loads/wave via global_load_lds;
// LDS f32 [64ch][256pos], linear dest, source-granule swizzle lane^((ch>>2)&7),
// read un-XORs to 2-way bank access.
__global__ __launch_bounds__(256) void transpose_feats(
    const float* __restrict__ p3, const float* __restrict__ p4, const float* __restrict__ p5,
    u16* __restrict__ t3, u16* __restrict__ t4, u16* __restrict__ t5) {
  __shared__ __align__(16) char smem[65536];
  const int bid = blockIdx.x;
  const int t = threadIdx.x;
  const int wave = t >> 6, lane = t & 63;
  float* lf = (float*)smem;
  const float* src; u16* dst; int S, tile;
  if (bid < 1024)      { src = p3; dst = t3; S = 128; tile = bid; }
  else if (bid < 1280) { src = p4; dst = t4; S = 64;  tile = bid - 1024; }
  else                 { src = p5; dst = t5; S = 32;  tile = bid - 1280; }
  const int cchunk = tile & 3;
  const int fp0 = (tile >> 2) * 256;   // flat pos (256-aligned; SS % 256 == 0)
  const int SS = S * S;
  const int b = fp0 / SS;
  const int pimg = fp0 - b * SS;
  const float* csrc = src + (size_t)(b * 256 + cchunk * 64) * SS + pimg;
#pragma unroll
  for (int g = 0; g < 16; ++g) {
    const int ch = g * 4 + wave;
    const int s = (ch >> 2) & 7;
    load_lds16(csrc + (size_t)ch * SS + ((lane ^ s) << 2),
               smem + ch * 1024);
  }
  __syncthreads();   // drains vmcnt(0)
  u16* dstb = dst + (size_t)fp0 * 256 + cchunk * 64;
#pragma unroll
  for (int j = 0; j < 16; ++j) {
    const int idx = t + 256 * j;        // [0,4096): 256 pos x 16 c4
    const int pos = idx >> 4;
    const int c4 = idx & 15;
    const int gb = (((pos >> 2) ^ (c4 & 7)) << 2) + (pos & 3);
    us4 o;
    o.x = f32_f16(lf[(4 * c4 + 0) * 256 + gb]);
    o.y = f32_f16(lf[(4 * c4 + 1) * 256 + gb]);
    o.z = f32_f16(lf[(4 * c4 + 2) * 256 + gb]);
    o.w = f32_f16(lf[(4 * c4 + 3) * 256 + gb]);
    *(us4*)(dstb + (size_t)pos * 256 + c4 * 4) = o;
  }
}

// ------- ROI align (2048 blocks) + W1 cvt (1568 blocks), 512 threads ----------
// v2: 8 waves/block (occupancy cap 32 waves/CU, was 34% measured at 4 waves) +
// xs stored via 16B-block XOR swizzle w^=((w>>9)&7)<<4 (exact involution; the
// linear uint4 copy-out un-swizzles) to break the 8-way bank conflict (2.4M).
__global__ __launch_bounds__(512) void roi_w1(
    const u16* __restrict__ t3, const u16* __restrict__ t4, const u16* __restrict__ t5,
    const float* __restrict__ bbox, const int* __restrict__ anchor,
    u16* __restrict__ X,
    const float* __restrict__ W1, u16* __restrict__ W1b) {
  __shared__ __align__(16) char smem[32768];
  const int bid = blockIdx.x;
  const int t = threadIdx.x;
  const int wave = t >> 6, lane = t & 63;
  if (bid >= 2048) {  // W1 f32 -> bf16 via async LDS staging (32KB/block)
    float* lf = (float*)smem;
    const size_t basef = (size_t)(bid - 2048) * 8192;   // f32 index
#pragma unroll
    for (int g = 0; g < 4; ++g)
      load_lds16(W1 + basef + wave * 1024 + g * 256 + lane * 4,
                 smem + wave * 4096 + g * 1024);
    __syncthreads();   // drains vmcnt(0)
    const size_t baseq = (size_t)(bid - 2048) * 2048;   // u64 quad index
#pragma unroll
    for (int j = 0; j < 4; ++j) {
      const int q = t + 512 * j;
      const float4 v = *(const float4*)&lf[q * 4];      // b128, conflict-free
      ((unsigned long long*)W1b)[baseq + q] = pack4bf(v);
    }
    return;
  }
  const int m = bid;
  const int b = m >> 9;
  const int lvl = anchor[m] / 3;
  const u16* ft; int S; float scale;
  if (lvl == 0)      { ft = t3; S = 128; scale = 0.125f;   }
  else if (lvl == 1) { ft = t4; S = 64;  scale = 0.0625f;  }
  else               { ft = t5; S = 32;  scale = 0.03125f; }
  ft += (size_t)b * S * S * 256;
  const float* bx = bbox + (size_t)m * 4;
  const float x1 = bx[0] * scale - 0.5f;
  const float y1 = bx[1] * scale - 0.5f;
  const float bw = (bx[2] * scale - 0.5f - x1) * (1.0f / 7.0f);
  const float bh = (bx[3] * scale - 0.5f - y1) * (1.0f / 7.0f);
  const float fS = (float)S;

  const int l = lane & 31, h = lane >> 5;
  const int cbase = l * 8;

#pragma unroll 1
  for (int it = 0; it < 4; ++it) {
    const int p = it * 16 + wave * 2 + h;   // 8 waves x 2 = 16 positions/iter
    if (p < 49) {
      const int py = p / 7, px = p - py * 7;
      h8 acc = splat8(0.0f);
#pragma unroll
      for (int sy = 0; sy < 2; ++sy) {
        const float y = y1 + bh * ((float)py + (sy ? 0.75f : 0.25f));
        const float my = (y >= -1.0f && y <= fS) ? 1.0f : 0.0f;
        const float cy = fminf(fmaxf(y, 0.0f), fS - 1.0f);
        const int y0 = (int)cy;
        const float ly = cy - (float)y0;
        const float hy = 1.0f - ly;
        const int y1i = (y0 + 1 < S) ? y0 + 1 : S - 1;
#pragma unroll
        for (int sx = 0; sx < 2; ++sx) {
          const float x = x1 + bw * ((float)px + (sx ? 0.75f : 0.25f));
          const float mx = (x >= -1.0f && x <= fS) ? 1.0f : 0.0f;
          const float cx = fminf(fmaxf(x, 0.0f), fS - 1.0f);
          const int x0 = (int)cx;
          const float lx = cx - (float)x0;
          const float hx = 1.0f - lx;
          const int x1i = (x0 + 1 < S) ? x0 + 1 : S - 1;
          const h8 f00 = *(const h8*)(ft + (size_t)(y0  * S + x0 ) * 256 + cbase);
          const h8 f01 = *(const h8*)(ft + (size_t)(y0  * S + x1i) * 256 + cbase);
          const h8 f10 = *(const h8*)(ft + (size_t)(y1i * S + x0 ) * 256 + cbase);
          const h8 f11 = *(const h8*)(ft + (size_t)(y1i * S + x1i) * 256 + cbase);
          const float msk = my * mx;
          acc += f00 * splat8(hy * hx * msk);
          acc += f01 * splat8(hy * lx * msk);
          acc += f10 * splat8(ly * hx * msk);
          acc += f11 * splat8(ly * lx * msk);
        }
      }
#pragma unroll
      for (int i = 0; i < 8; ++i) {
        const int w = ((cbase + i) * 49 + p) * 2;
        *(u16*)(smem + (w ^ (((w >> 9) & 7) << 4))) = f32_bf16((float)acc[i] * 0.25f);
      }
    }
  }
  __syncthreads();
  uint4* dst = (uint4*)(X + (size_t)m * 12544);
  for (int i = t; i < 1568; i += 512) {
    const int bb = i * 16;
    dst[i] = *(const uint4*)(smem + (bb ^ (((bb >> 9) & 7) << 4)));
  }
}

// ============ 256x256 phase-split pipelined BT-GEMM (bf16 partials out) =======
// ROUND-7 EXACT schedule (measured optimum). 8 waves (2M x 4N), BK=64, two
// K-half phases: vmcnt(4) -> s_barrier -> sched_barrier -> 12 ds_read_b128 ->
// stage(t+1,ph) -> setprio(1) 32 MFMA setprio(0).
// LDS 128 KiB, st-swizzle byte^=(rowpair&7)<<4 on global source + LDS read.
// Uneven split-K=8 (z<4: 25 K-tiles, else 24).
__global__ __launch_bounds__(512, 2)
void gemm8_bt(const u16* __restrict__ A, int lda,
              const u16* __restrict__ B, int ldb,
              u16* __restrict__ Cpart, int M, int N,
              int mb, int nb) {
  __shared__ __align__(16) char lds[131072];
  const int tid = threadIdx.x;
  const int wave = tid >> 6, lane = tid & 63;
  const int wr = wave >> 2, wc = wave & 3;

  const int G = gridDim.x;
  const int bid = blockIdx.x;
  const int swz = (bid & 7) * (G >> 3) + (bid >> 3);
  const int x = swz % mb;
  const int rest = swz / mb;
  const int y = rest % nb;
  const int z = rest / nb;
  const int m0 = x * 256, n0 = y * 256;
  const int nt = 24 + (z < 4 ? 1 : 0);
  const int kb0 = (z * 24 + (z < 4 ? z : 4)) * 64;

  const int sb = ((lane & 7) ^ (lane >> 3)) << 4;
  const int rowb2 = 2 * (wave * 8 + (lane >> 3)) + (sb >> 6);
  const int keloff = (sb & 63) >> 1;

  const int frow = lane & 15;
  const int rh = frow >> 1;
  const int swb = ((((frow & 1) << 6) | ((lane >> 4) << 4))) ^ (rh << 4);
  const int a_rd = wr * 8192 + rh * 128 + swb;
  const int b_rd = wc * 4096 + rh * 128 + swb;

  f32x4 acc[8][4];
#pragma unroll
  for (int i = 0; i < 8; ++i)
#pragma unroll
    for (int j = 0; j < 4; ++j)
      acc[i][j] = f32x4{0.f, 0.f, 0.f, 0.f};

  auto stageAB = [&](int tile, int ph) {
    const int dst = ((tile & 1) * 2 + ph) * 16384;
    const int kel = kb0 + tile * 64 + ph * 32 + keloff;
#pragma unroll
    for (int i = 0; i < 2; ++i) {
      const u16* srcA = A + (size_t)(m0 + i * 128 + rowb2) * lda + kel;
      load_lds16(srcA, lds + dst + i * 8192 + wave * 1024);
    }
#pragma unroll
    for (int i = 0; i < 2; ++i) {
      const u16* srcB = B + (size_t)(n0 + i * 128 + rowb2) * ldb + kel;
      load_lds16(srcB, lds + 65536 + dst + i * 8192 + wave * 1024);
    }
  };

#define GPHASE(T, PH, VW, DOSTAGE)                                              \
  {                                                                             \
    asm volatile("s_waitcnt vmcnt(" VW ")" ::: "memory");                       \
    __builtin_amdgcn_s_barrier();                                               \
    __builtin_amdgcn_sched_barrier(0);                                          \
    const int hb_ = (((T) & 1) * 2 + (PH)) * 16384;                             \
    short8 af[8], bf[4];                                                        \
    _Pragma("unroll")                                                           \
    for (int fi = 0; fi < 8; ++fi)                                              \
      af[fi] = *(const short8*)(lds + hb_ + a_rd + fi * 1024);                  \
    _Pragma("unroll")                                                           \
    for (int fj = 0; fj < 4; ++fj)                                              \
      bf[fj] = *(const short8*)(lds + 65536 + hb_ + b_rd + fj * 1024);          \
    if (DOSTAGE) stageAB((T) + 1, (PH));                                        \
    __builtin_amdgcn_s_setprio(1);                                              \
    _Pragma("unroll")                                                           \
    for (int fi = 0; fi < 8; ++fi) {                                            \
      _Pragma("unroll")                                                         \
      for (int fj = 0; fj < 4; ++fj)                                            \
        acc[fi][fj] = __builtin_amdgcn_mfma_f32_16x16x32_bf16(af[fi], bf[fj],   \
                                                              acc[fi][fj], 0, 0, 0); \
    }                                                                           \
    __builtin_amdgcn_s_setprio(0);                                              \
  }

  stageAB(0, 0);
  stageAB(0, 1);
#pragma unroll 1
  for (int t = 0; t < nt - 1; ++t) {
    GPHASE(t, 0, "4", true);
    GPHASE(t, 1, "4", true);
  }
  GPHASE(nt - 1, 0, "4", false);
  GPHASE(nt - 1, 1, "0", false);
#undef GPHASE

  u16* Cp = Cpart + (size_t)z * ((size_t)M * N);
  const int rq = (lane >> 4) * 4;
  const int cq = lane & 15;
#pragma unroll
  for (int fi = 0; fi < 8; ++fi)
#pragma unroll
    for (int fj = 0; fj < 4; ++fj) {
      const int row = m0 + wr * 128 + fi * 16 + rq;
      const int col = n0 + wc * 64 + fj * 16 + cq;
#pragma unroll
      for (int q = 0; q < 4; ++q)
        Cp[(size_t)(row + q) * N + col] = f32_bf16(acc[fi][fj][q]);
    }
}

// --- FC1 reduction (2048 blocks) + W2 cvt (1024) + Wp cvt (96) merged ---------
__global__ __launch_bounds__(256) void reduce_cvt(
    const u16* __restrict__ P8, const float* __restrict__ bias,
    u16* __restrict__ out,
    const float* __restrict__ W2, const float* __restrict__ Wp,
    u16* __restrict__ W2b, u16* __restrict__ Wpb) {
  const int bid = blockIdx.x;
  if (bid >= 3072) {  // Wp: 96 blocks, pad 93x1024 -> 96x1024
    const int i = (bid - 3072) * 256 + threadIdx.x;
    float4 v = (i * 4 < 95232) ? ((const float4*)Wp)[i] : float4{0.f, 0.f, 0.f, 0.f};
    ((unsigned long long*)Wpb)[i] = pack4bf(v);
    return;
  }
  if (bid >= 2048) {  // W2: 1024 blocks
    const int i = (bid - 2048) * 256 + threadIdx.x;
    ((unsigned long long*)W2b)[i] = pack4bf(((const float4*)W2)[i]);
    return;
  }
  const int i4 = (bid * 256 + threadIdx.x) * 4;
  const int nb = i4 & 1023;
  float s0 = bias[nb], s1 = bias[nb + 1], s2 = bias[nb + 2], s3 = bias[nb + 3];
#pragma unroll
  for (int j = 0; j < 8; ++j) {
    const us4 v = *(const us4*)(P8 + (size_t)j * 2097152 + i4);
    s0 += bf16_f32(v.x); s1 += bf16_f32(v.y); s2 += bf16_f32(v.z); s3 += bf16_f32(v.w);
  }
  us4 o;
  o.x = f32_bf16(fmaxf(s0, 0.f)); o.y = f32_bf16(fmaxf(s1, 0.f));
  o.z = f32_bf16(fmaxf(s2, 0.f)); o.w = f32_bf16(fmaxf(s3, 0.f));
  *(us4*)(out + i4) = o;
}

// ---------------- old split-K BT-GEMM (f32 partials) for FC2 / proj -----------
template<int BM, int BN, int WGM, int WGN>
__global__ __launch_bounds__(256)
void gemm_bt_splitk(const u16* __restrict__ A, int lda,
                    const u16* __restrict__ B, int ldb,
                    float* __restrict__ Cpart, int M, int N, int Ksplit) {
  constexpr int BK = 64;
  constexpr int WM = BM / WGM, WN = BN / WGN;
  constexpr int FM = WM / 16, FN = WN / 16;
  constexpr int AITER = BM * BK / 2048;
  constexpr int BITER = BN * BK / 2048;
  __shared__ u16 Asm_[BM * BK];
  __shared__ u16 Bsm_[BN * BK];
  const int tid = threadIdx.x;
  const int wave = tid >> 6, lane = tid & 63;
  const int wr = wave / WGN, wc = wave % WGN;
  const int m0 = blockIdx.x * BM, n0 = blockIdx.y * BN;
  const int kbase0 = blockIdx.z * Ksplit;

  f32x4 acc[FM][FN];
#pragma unroll
  for (int i = 0; i < FM; ++i)
#pragma unroll
    for (int j = 0; j < FN; ++j)
      acc[i][j] = f32x4{0.0f, 0.0f, 0.0f, 0.0f};

  const int ar = tid >> 3;
  const int acsub = (tid & 7) * 8;
  const int fr = lane & 15;
  const int kq = (lane >> 4) * 8;

  for (int kt = 0; kt < Ksplit; kt += BK) {
    const int kb = kbase0 + kt;
#pragma unroll
    for (int it = 0; it < AITER; ++it) {
      const u16* src = A + (size_t)(m0 + it * 32 + ar) * lda + kb + acsub;
      load_lds16(src, (char*)Asm_ + it * 4096 + wave * 1024);
    }
#pragma unroll
    for (int it = 0; it < BITER; ++it) {
      const u16* src = B + (size_t)(n0 + it * 32 + ar) * ldb + kb + acsub;
      load_lds16(src, (char*)Bsm_ + it * 4096 + wave * 1024);
    }
    __syncthreads();
#pragma unroll
    for (int kk = 0; kk < BK; kk += 32) {
      short8 af[FM], bfr[FN];
#pragma unroll
      for (int i = 0; i < FM; ++i)
        af[i] = *(const short8*)(Asm_ + (wr * WM + i * 16 + fr) * BK + kk + kq);
#pragma unroll
      for (int j = 0; j < FN; ++j)
        bfr[j] = *(const short8*)(Bsm_ + (wc * WN + j * 16 + fr) * BK + kk + kq);
#pragma unroll
      for (int i = 0; i < FM; ++i)
#pragma unroll
        for (int j = 0; j < FN; ++j)
          acc[i][j] = __builtin_amdgcn_mfma_f32_16x16x32_bf16(af[i], bfr[j], acc[i][j], 0, 0, 0);
    }
    __syncthreads();
  }

  float* Cp = Cpart + (size_t)blockIdx.z * ((size_t)M * N);
  const int rq = (lane >> 4) * 4;
  const int cq = lane & 15;
#pragma unroll
  for (int i = 0; i < FM; ++i)
#pragma unroll
    for (int j = 0; j < FN; ++j) {
      const int row = m0 + wr * WM + i * 16 + rq;
      const int col = n0 + wc * WN + j * 16 + cq;
      float* o = Cp + (size_t)row * N + col;
#pragma unroll
      for (int q = 0; q < 4; ++q)
        o[(size_t)q * N] = acc[i][j][q];
    }
}

template<int S, bool RELU>
__global__ __launch_bounds__(256) void reduce_bias_bf16(
    const float* __restrict__ P, const float* __restrict__ bias,
    u16* __restrict__ out, int MN, int Nmask) {
  const int i = blockIdx.x * 256 + threadIdx.x;
  if (i >= MN) return;
  float s = bias[i & Nmask];
#pragma unroll
  for (int j = 0; j < S; ++j) s += P[(size_t)j * MN + i];
  if (RELU) s = fmaxf(s, 0.0f);
  out[i] = f32_bf16(s);
}

__global__ __launch_bounds__(256) void reduce_out(
    const float* __restrict__ P, const float* __restrict__ bp,
    float* __restrict__ out) {
  const int i = blockIdx.x * 256 + threadIdx.x;
  if (i >= 2048 * 93) return;
  const int mrow = i / 93;
  const int n = i - mrow * 93;
  float s = bp[n];
#pragma unroll
  for (int j = 0; j < 8; ++j) s += P[(size_t)j * (2048 * 96) + mrow * 96 + n];
  out[i] = s;
}

// ---------------- launch ------------------------------------------------------
extern "C" void kernel_launch(void* const* d_in, const int* in_sizes, int n_in,
                              void* d_out, int out_size, void* d_ws, size_t ws_size,
                              hipStream_t stream) {
  const float* p3   = (const float*)d_in[0];
  const float* p4   = (const float*)d_in[1];
  const float* p5   = (const float*)d_in[2];
  const float* bbox = (const float*)d_in[3];
  const int*   anc  = (const int*)d_in[4];
  const float* W1   = (const float*)d_in[5];
  const float* b1   = (const float*)d_in[6];
  const float* W2   = (const float*)d_in[7];
  const float* b2   = (const float*)d_in[8];
  const float* Wp   = (const float*)d_in[9];
  const float* bp   = (const float*)d_in[10];
  float* out = (float*)d_out;

  char* ws = (char*)d_ws;
  // Permanent: X [0, 51380224), W1b [51380224, 77070336)
  u16* X   = (u16*)(ws);
  u16* W1b = (u16*)(ws + 51380224);
  // Shared region R at 77070336 (size 44236800; total 121307136 B, proven fit):
  //   Phase A (transpose+roi): t3|t4|t5 fp16 (44040192 B)
  //   Phase B (after roi): W2b|Wpb|H1|H2|{P8 bf16 33554432 / Pf f32 <=16777216}
  char* R = ws + 77070336;
  u16* t3  = (u16*)(R);
  u16* t4  = (u16*)(R + 33554432);
  u16* t5  = (u16*)(R + 41943040);
  u16* W2b = (u16*)(R);
  u16* Wpb = (u16*)(R + 2097152);
  u16* H1  = (u16*)(R + 2293760);
  u16* H2  = (u16*)(R + 6488064);
  u16*   P8 = (u16*)(R + 10682368);   // 8 x 2048x1024 bf16 (FC1 partials)
  float* Pf = (float*)(R + 10682368); // f32 partials for FC2/proj (reuse)
  (void)ws_size; (void)in_sizes; (void)n_in; (void)out_size;

  // Phase A: feats -> channels-last fp16 (feat-only), then ROI + W1 cvt merged
  hipLaunchKernelGGL(transpose_feats, dim3(1344), dim3(256), 0, stream,
                     p3, p4, p5, t3, t4, t5);
  hipLaunchKernelGGL(roi_w1, dim3(3616), dim3(512), 0, stream,
                     t3, t4, t5, bbox, anc, X, W1, W1b);
  // FC1: X @ W1^T — 256² 2-phase pipeline (round-7 exact), uneven split-K=8
  hipLaunchKernelGGL(gemm8_bt, dim3(256), dim3(512), 0, stream,
                     X, 12544, W1b, 12544, P8, 2048, 1024, 8, 4);
  // FC1 reduce + bias + ReLU, merged with W2/Wp cvt (aliases t3: roi is done)
  hipLaunchKernelGGL(reduce_cvt, dim3(3168), dim3(256), 0, stream,
                     P8, b1, H1, W2, Wp, W2b, Wpb);
  // FC2: H1 @ W2^T, split-K=2 (old structure)
  hipLaunchKernelGGL((gemm_bt_splitk<128,128,2,2>), dim3(16, 8, 2), dim3(256), 0, stream,
                     H1, 1024, W2b, 1024, Pf, 2048, 1024, 512);
  hipLaunchKernelGGL((reduce_bias_bf16<2,true>), dim3(8192), dim3(256), 0, stream,
                     Pf, b2, H2, 2048 * 1024, 1023);
  // proj: H2 @ Wp^T (N padded to 96), split-K=8
  hipLaunchKernelGGL((gemm_bt_splitk<128,96,4,1>), dim3(16, 1, 8), dim3(256), 0, stream,
                     H2, 1024, Wpb, 1024, Pf, 2048, 96, 128);
  hipLaunchKernelGGL(reduce_out, dim3(744), dim3(256), 0, stream, Pf, bp, out);
}

// Round 21
// 155.585 us; speedup vs baseline: 1.0120x; 1.0120x over previous
//
#include <hip/hip_runtime.h>
#include <hip/hip_bf16.h>

typedef unsigned short u16;
typedef __attribute__((ext_vector_type(8))) short short8;
typedef __attribute__((ext_vector_type(4))) float f32x4;
typedef __attribute__((ext_vector_type(4))) unsigned short us4;
typedef __attribute__((ext_vector_type(8))) _Float16 h8;

__device__ __forceinline__ u16 f32_bf16(float f) {
  union { float f; unsigned int u; } v; v.f = f;
  unsigned int r = v.u + 0x7fffu + ((v.u >> 16) & 1u);  // round-to-nearest-even
  return (u16)(r >> 16);
}
__device__ __forceinline__ float bf16_f32(u16 h) {
  union { unsigned int u; float f; } v; v.u = ((unsigned int)h) << 16; return v.f;
}
__device__ __forceinline__ u16 f32_f16(float f) {
  union { _Float16 h; u16 u; } v; v.h = (_Float16)f; return v.u;
}
__device__ __forceinline__ h8 splat8(float f) {
  _Float16 h = (_Float16)f;
  h8 r = {h, h, h, h, h, h, h, h};
  return r;
}
__device__ __forceinline__ unsigned long long pack4bf(float4 v) {
  return (unsigned long long)f32_bf16(v.x)
       | ((unsigned long long)f32_bf16(v.y) << 16)
       | ((unsigned long long)f32_bf16(v.z) << 32)
       | ((unsigned long long)f32_bf16(v.w) << 48);
}

__device__ __forceinline__ void load_lds16(const void* g, void* l) {
  __builtin_amdgcn_global_load_lds((const __attribute__((address_space(1))) unsigned int*)g,
                                   (__attribute__((address_space(3))) unsigned int*)l,
                                   16, 0, 0);
}

// ------- feature transpose ONLY (1344 blocks) ---------------------------------
// Async-staged: 16 outstanding 1KB channel loads/wave via global_load_lds;
// LDS f32 [64ch][256pos], linear dest, source-granule swizzle lane^((ch>>2)&7),
// read un-XORs to 2-way bank access.
__global__ __launch_bounds__(256) void transpose_feats(
    const float* __restrict__ p3, const float* __restrict__ p4, const float* __restrict__ p5,
    u16* __restrict__ t3, u16* __restrict__ t4, u16* __restrict__ t5) {
  __shared__ __align__(16) char smem[65536];
  const int bid = blockIdx.x;
  const int t = threadIdx.x;
  const int wave = t >> 6, lane = t & 63;
  float* lf = (float*)smem;
  const float* src; u16* dst; int S, tile;
  if (bid < 1024)      { src = p3; dst = t3; S = 128; tile = bid; }
  else if (bid < 1280) { src = p4; dst = t4; S = 64;  tile = bid - 1024; }
  else                 { src = p5; dst = t5; S = 32;  tile = bid - 1280; }
  const int cchunk = tile & 3;
  const int fp0 = (tile >> 2) * 256;   // flat pos (256-aligned; SS % 256 == 0)
  const int SS = S * S;
  const int b = fp0 / SS;
  const int pimg = fp0 - b * SS;
  const float* csrc = src + (size_t)(b * 256 + cchunk * 64) * SS + pimg;
#pragma unroll
  for (int g = 0; g < 16; ++g) {
    const int ch = g * 4 + wave;
    const int s = (ch >> 2) & 7;
    load_lds16(csrc + (size_t)ch * SS + ((lane ^ s) << 2),
               smem + ch * 1024);
  }
  __syncthreads();   // drains vmcnt(0)
  u16* dstb = dst + (size_t)fp0 * 256 + cchunk * 64;
#pragma unroll
  for (int j = 0; j < 16; ++j) {
    const int idx = t + 256 * j;        // [0,4096): 256 pos x 16 c4
    const int pos = idx >> 4;
    const int c4 = idx & 15;
    const int gb = (((pos >> 2) ^ (c4 & 7)) << 2) + (pos & 3);
    us4 o;
    o.x = f32_f16(lf[(4 * c4 + 0) * 256 + gb]);
    o.y = f32_f16(lf[(4 * c4 + 1) * 256 + gb]);
    o.z = f32_f16(lf[(4 * c4 + 2) * 256 + gb]);
    o.w = f32_f16(lf[(4 * c4 + 3) * 256 + gb]);
    *(us4*)(dstb + (size_t)pos * 256 + c4 * 4) = o;
  }
}

// ------- ROI align (2048 blocks) + W1 cvt (1568 blocks), 512 threads ----------
// v3: IMAGE-LOCALITY XCD REMAP — m = ((bid&7)<<8)|(bid>>3) (bijective) pins
// image m>>9 to XCD pair {2i,2i+1} (XCD = bid%8), so each per-XCD L2 caches
// ~10.6MB of ONE image instead of all four (42MB thrash -> 87MB FETCH at 2x
// re-fetch measured in r19/r20). xs staging reverted to plain layout (the r20
// swizzle raised conflicts 2.4M->3.5M).
__global__ __launch_bounds__(512) void roi_w1(
    const u16* __restrict__ t3, const u16* __restrict__ t4, const u16* __restrict__ t5,
    const float* __restrict__ bbox, const int* __restrict__ anchor,
    u16* __restrict__ X,
    const float* __restrict__ W1, u16* __restrict__ W1b) {
  __shared__ __align__(16) char smem[32768];
  const int bid = blockIdx.x;
  const int t = threadIdx.x;
  const int wave = t >> 6, lane = t & 63;
  if (bid >= 2048) {  // W1 f32 -> bf16 via async LDS staging (32KB/block)
    float* lf = (float*)smem;
    const size_t basef = (size_t)(bid - 2048) * 8192;   // f32 index
#pragma unroll
    for (int g = 0; g < 4; ++g)
      load_lds16(W1 + basef + wave * 1024 + g * 256 + lane * 4,
                 smem + wave * 4096 + g * 1024);
    __syncthreads();   // drains vmcnt(0)
    const size_t baseq = (size_t)(bid - 2048) * 2048;   // u64 quad index
#pragma unroll
    for (int j = 0; j < 4; ++j) {
      const int q = t + 512 * j;
      const float4 v = *(const float4*)&lf[q * 4];      // b128, conflict-free
      ((unsigned long long*)W1b)[baseq + q] = pack4bf(v);
    }
    return;
  }
  u16* xs = (u16*)smem;   // 12544 u16 = 25088 B (plain layout)
  const int m = ((bid & 7) << 8) | (bid >> 3);  // image-locality XCD remap
  const int b = m >> 9;
  const int lvl = anchor[m] / 3;
  const u16* ft; int S; float scale;
  if (lvl == 0)      { ft = t3; S = 128; scale = 0.125f;   }
  else if (lvl == 1) { ft = t4; S = 64;  scale = 0.0625f;  }
  else               { ft = t5; S = 32;  scale = 0.03125f; }
  ft += (size_t)b * S * S * 256;
  const float* bx = bbox + (size_t)m * 4;
  const float x1 = bx[0] * scale - 0.5f;
  const float y1 = bx[1] * scale - 0.5f;
  const float bw = (bx[2] * scale - 0.5f - x1) * (1.0f / 7.0f);
  const float bh = (bx[3] * scale - 0.5f - y1) * (1.0f / 7.0f);
  const float fS = (float)S;

  const int l = lane & 31, h = lane >> 5;
  const int cbase = l * 8;

#pragma unroll 1
  for (int it = 0; it < 4; ++it) {
    const int p = it * 16 + wave * 2 + h;   // 8 waves x 2 = 16 positions/iter
    if (p < 49) {
      const int py = p / 7, px = p - py * 7;
      h8 acc = splat8(0.0f);
#pragma unroll
      for (int sy = 0; sy < 2; ++sy) {
        const float y = y1 + bh * ((float)py + (sy ? 0.75f : 0.25f));
        const float my = (y >= -1.0f && y <= fS) ? 1.0f : 0.0f;
        const float cy = fminf(fmaxf(y, 0.0f), fS - 1.0f);
        const int y0 = (int)cy;
        const float ly = cy - (float)y0;
        const float hy = 1.0f - ly;
        const int y1i = (y0 + 1 < S) ? y0 + 1 : S - 1;
#pragma unroll
        for (int sx = 0; sx < 2; ++sx) {
          const float x = x1 + bw * ((float)px + (sx ? 0.75f : 0.25f));
          const float mx = (x >= -1.0f && x <= fS) ? 1.0f : 0.0f;
          const float cx = fminf(fmaxf(x, 0.0f), fS - 1.0f);
          const int x0 = (int)cx;
          const float lx = cx - (float)x0;
          const float hx = 1.0f - lx;
          const int x1i = (x0 + 1 < S) ? x0 + 1 : S - 1;
          const h8 f00 = *(const h8*)(ft + (size_t)(y0  * S + x0 ) * 256 + cbase);
          const h8 f01 = *(const h8*)(ft + (size_t)(y0  * S + x1i) * 256 + cbase);
          const h8 f10 = *(const h8*)(ft + (size_t)(y1i * S + x0 ) * 256 + cbase);
          const h8 f11 = *(const h8*)(ft + (size_t)(y1i * S + x1i) * 256 + cbase);
          const float msk = my * mx;
          acc += f00 * splat8(hy * hx * msk);
          acc += f01 * splat8(hy * lx * msk);
          acc += f10 * splat8(ly * hx * msk);
          acc += f11 * splat8(ly * lx * msk);
        }
      }
#pragma unroll
      for (int i = 0; i < 8; ++i)
        xs[(cbase + i) * 49 + p] = f32_bf16((float)acc[i] * 0.25f);
    }
  }
  __syncthreads();
  uint4* dst = (uint4*)(X + (size_t)m * 12544);
  const uint4* srcl = (const uint4*)xs;
  for (int i = t; i < 1568; i += 512) dst[i] = srcl[i];
}

// ============ 256x256 phase-split pipelined BT-GEMM (bf16 partials out) =======
// ROUND-7 EXACT schedule (measured optimum). 8 waves (2M x 4N), BK=64, two
// K-half phases: vmcnt(4) -> s_barrier -> sched_barrier -> 12 ds_read_b128 ->
// stage(t+1,ph) -> setprio(1) 32 MFMA setprio(0).
// LDS 128 KiB, st-swizzle byte^=(rowpair&7)<<4 on global source + LDS read.
// Uneven split-K=8 (z<4: 25 K-tiles, else 24).
__global__ __launch_bounds__(512, 2)
void gemm8_bt(const u16* __restrict__ A, int lda,
              const u16* __restrict__ B, int ldb,
              u16* __restrict__ Cpart, int M, int N,
              int mb, int nb) {
  __shared__ __align__(16) char lds[131072];
  const int tid = threadIdx.x;
  const int wave = tid >> 6, lane = tid & 63;
  const int wr = wave >> 2, wc = wave & 3;

  const int G = gridDim.x;
  const int bid = blockIdx.x;
  const int swz = (bid & 7) * (G >> 3) + (bid >> 3);
  const int x = swz % mb;
  const int rest = swz / mb;
  const int y = rest % nb;
  const int z = rest / nb;
  const int m0 = x * 256, n0 = y * 256;
  const int nt = 24 + (z < 4 ? 1 : 0);
  const int kb0 = (z * 24 + (z < 4 ? z : 4)) * 64;

  const int sb = ((lane & 7) ^ (lane >> 3)) << 4;
  const int rowb2 = 2 * (wave * 8 + (lane >> 3)) + (sb >> 6);
  const int keloff = (sb & 63) >> 1;

  const int frow = lane & 15;
  const int rh = frow >> 1;
  const int swb = ((((frow & 1) << 6) | ((lane >> 4) << 4))) ^ (rh << 4);
  const int a_rd = wr * 8192 + rh * 128 + swb;
  const int b_rd = wc * 4096 + rh * 128 + swb;

  f32x4 acc[8][4];
#pragma unroll
  for (int i = 0; i < 8; ++i)
#pragma unroll
    for (int j = 0; j < 4; ++j)
      acc[i][j] = f32x4{0.f, 0.f, 0.f, 0.f};

  auto stageAB = [&](int tile, int ph) {
    const int dst = ((tile & 1) * 2 + ph) * 16384;
    const int kel = kb0 + tile * 64 + ph * 32 + keloff;
#pragma unroll
    for (int i = 0; i < 2; ++i) {
      const u16* srcA = A + (size_t)(m0 + i * 128 + rowb2) * lda + kel;
      load_lds16(srcA, lds + dst + i * 8192 + wave * 1024);
    }
#pragma unroll
    for (int i = 0; i < 2; ++i) {
      const u16* srcB = B + (size_t)(n0 + i * 128 + rowb2) * ldb + kel;
      load_lds16(srcB, lds + 65536 + dst + i * 8192 + wave * 1024);
    }
  };

#define GPHASE(T, PH, VW, DOSTAGE)                                              \
  {                                                                             \
    asm volatile("s_waitcnt vmcnt(" VW ")" ::: "memory");                       \
    __builtin_amdgcn_s_barrier();                                               \
    __builtin_amdgcn_sched_barrier(0);                                          \
    const int hb_ = (((T) & 1) * 2 + (PH)) * 16384;                             \
    short8 af[8], bf[4];                                                        \
    _Pragma("unroll")                                                           \
    for (int fi = 0; fi < 8; ++fi)                                              \
      af[fi] = *(const short8*)(lds + hb_ + a_rd + fi * 1024);                  \
    _Pragma("unroll")                                                           \
    for (int fj = 0; fj < 4; ++fj)                                              \
      bf[fj] = *(const short8*)(lds + 65536 + hb_ + b_rd + fj * 1024);          \
    if (DOSTAGE) stageAB((T) + 1, (PH));                                        \
    __builtin_amdgcn_s_setprio(1);                                              \
    _Pragma("unroll")                                                           \
    for (int fi = 0; fi < 8; ++fi) {                                            \
      _Pragma("unroll")                                                         \
      for (int fj = 0; fj < 4; ++fj)                                            \
        acc[fi][fj] = __builtin_amdgcn_mfma_f32_16x16x32_bf16(af[fi], bf[fj],   \
                                                              acc[fi][fj], 0, 0, 0); \
    }                                                                           \
    __builtin_amdgcn_s_setprio(0);                                              \
  }

  stageAB(0, 0);
  stageAB(0, 1);
#pragma unroll 1
  for (int t = 0; t < nt - 1; ++t) {
    GPHASE(t, 0, "4", true);
    GPHASE(t, 1, "4", true);
  }
  GPHASE(nt - 1, 0, "4", false);
  GPHASE(nt - 1, 1, "0", false);
#undef GPHASE

  u16* Cp = Cpart + (size_t)z * ((size_t)M * N);
  const int rq = (lane >> 4) * 4;
  const int cq = lane & 15;
#pragma unroll
  for (int fi = 0; fi < 8; ++fi)
#pragma unroll
    for (int fj = 0; fj < 4; ++fj) {
      const int row = m0 + wr * 128 + fi * 16 + rq;
      const int col = n0 + wc * 64 + fj * 16 + cq;
#pragma unroll
      for (int q = 0; q < 4; ++q)
        Cp[(size_t)(row + q) * N + col] = f32_bf16(acc[fi][fj][q]);
    }
}

// --- FC1 reduction (2048 blocks) + W2 cvt (1024) + Wp cvt (96) merged ---------
__global__ __launch_bounds__(256) void reduce_cvt(
    const u16* __restrict__ P8, const float* __restrict__ bias,
    u16* __restrict__ out,
    const float* __restrict__ W2, const float* __restrict__ Wp,
    u16* __restrict__ W2b, u16* __restrict__ Wpb) {
  const int bid = blockIdx.x;
  if (bid >= 3072) {  // Wp: 96 blocks, pad 93x1024 -> 96x1024
    const int i = (bid - 3072) * 256 + threadIdx.x;
    float4 v = (i * 4 < 95232) ? ((const float4*)Wp)[i] : float4{0.f, 0.f, 0.f, 0.f};
    ((unsigned long long*)Wpb)[i] = pack4bf(v);
    return;
  }
  if (bid >= 2048) {  // W2: 1024 blocks
    const int i = (bid - 2048) * 256 + threadIdx.x;
    ((unsigned long long*)W2b)[i] = pack4bf(((const float4*)W2)[i]);
    return;
  }
  const int i4 = (bid * 256 + threadIdx.x) * 4;
  const int nb = i4 & 1023;
  float s0 = bias[nb], s1 = bias[nb + 1], s2 = bias[nb + 2], s3 = bias[nb + 3];
#pragma unroll
  for (int j = 0; j < 8; ++j) {
    const us4 v = *(const us4*)(P8 + (size_t)j * 2097152 + i4);
    s0 += bf16_f32(v.x); s1 += bf16_f32(v.y); s2 += bf16_f32(v.z); s3 += bf16_f32(v.w);
  }
  us4 o;
  o.x = f32_bf16(fmaxf(s0, 0.f)); o.y = f32_bf16(fmaxf(s1, 0.f));
  o.z = f32_bf16(fmaxf(s2, 0.f)); o.w = f32_bf16(fmaxf(s3, 0.f));
  *(us4*)(out + i4) = o;
}

// ---------------- old split-K BT-GEMM (f32 partials) for FC2 / proj -----------
template<int BM, int BN, int WGM, int WGN>
__global__ __launch_bounds__(256)
void gemm_bt_splitk(const u16* __restrict__ A, int lda,
                    const u16* __restrict__ B, int ldb,
                    float* __restrict__ Cpart, int M, int N, int Ksplit) {
  constexpr int BK = 64;
  constexpr int WM = BM / WGM, WN = BN / WGN;
  constexpr int FM = WM / 16, FN = WN / 16;
  constexpr int AITER = BM * BK / 2048;
  constexpr int BITER = BN * BK / 2048;
  __shared__ u16 Asm_[BM * BK];
  __shared__ u16 Bsm_[BN * BK];
  const int tid = threadIdx.x;
  const int wave = tid >> 6, lane = tid & 63;
  const int wr = wave / WGN, wc = wave % WGN;
  const int m0 = blockIdx.x * BM, n0 = blockIdx.y * BN;
  const int kbase0 = blockIdx.z * Ksplit;

  f32x4 acc[FM][FN];
#pragma unroll
  for (int i = 0; i < FM; ++i)
#pragma unroll
    for (int j = 0; j < FN; ++j)
      acc[i][j] = f32x4{0.0f, 0.0f, 0.0f, 0.0f};

  const int ar = tid >> 3;
  const int acsub = (tid & 7) * 8;
  const int fr = lane & 15;
  const int kq = (lane >> 4) * 8;

  for (int kt = 0; kt < Ksplit; kt += BK) {
    const int kb = kbase0 + kt;
#pragma unroll
    for (int it = 0; it < AITER; ++it) {
      const u16* src = A + (size_t)(m0 + it * 32 + ar) * lda + kb + acsub;
      load_lds16(src, (char*)Asm_ + it * 4096 + wave * 1024);
    }
#pragma unroll
    for (int it = 0; it < BITER; ++it) {
      const u16* src = B + (size_t)(n0 + it * 32 + ar) * ldb + kb + acsub;
      load_lds16(src, (char*)Bsm_ + it * 4096 + wave * 1024);
    }
    __syncthreads();
#pragma unroll
    for (int kk = 0; kk < BK; kk += 32) {
      short8 af[FM], bfr[FN];
#pragma unroll
      for (int i = 0; i < FM; ++i)
        af[i] = *(const short8*)(Asm_ + (wr * WM + i * 16 + fr) * BK + kk + kq);
#pragma unroll
      for (int j = 0; j < FN; ++j)
        bfr[j] = *(const short8*)(Bsm_ + (wc * WN + j * 16 + fr) * BK + kk + kq);
#pragma unroll
      for (int i = 0; i < FM; ++i)
#pragma unroll
        for (int j = 0; j < FN; ++j)
          acc[i][j] = __builtin_amdgcn_mfma_f32_16x16x32_bf16(af[i], bfr[j], acc[i][j], 0, 0, 0);
    }
    __syncthreads();
  }

  float* Cp = Cpart + (size_t)blockIdx.z * ((size_t)M * N);
  const int rq = (lane >> 4) * 4;
  const int cq = lane & 15;
#pragma unroll
  for (int i = 0; i < FM; ++i)
#pragma unroll
    for (int j = 0; j < FN; ++j) {
      const int row = m0 + wr * WM + i * 16 + rq;
      const int col = n0 + wc * WN + j * 16 + cq;
      float* o = Cp + (size_t)row * N + col;
#pragma unroll
      for (int q = 0; q < 4; ++q)
        o[(size_t)q * N] = acc[i][j][q];
    }
}

template<int S, bool RELU>
__global__ __launch_bounds__(256) void reduce_bias_bf16(
    const float* __restrict__ P, const float* __restrict__ bias,
    u16* __restrict__ out, int MN, int Nmask) {
  const int i = blockIdx.x * 256 + threadIdx.x;
  if (i >= MN) return;
  float s = bias[i & Nmask];
#pragma unroll
  for (int j = 0; j < S; ++j) s += P[(size_t)j * MN + i];
  if (RELU) s = fmaxf(s, 0.0f);
  out[i] = f32_bf16(s);
}

__global__ __launch_bounds__(256) void reduce_out(
    const float* __restrict__ P, const float* __restrict__ bp,
    float* __restrict__ out) {
  const int i = blockIdx.x * 256 + threadIdx.x;
  if (i >= 2048 * 93) return;
  const int mrow = i / 93;
  const int n = i - mrow * 93;
  float s = bp[n];
#pragma unroll
  for (int j = 0; j < 8; ++j) s += P[(size_t)j * (2048 * 96) + mrow * 96 + n];
  out[i] = s;
}

// ---------------- launch ------------------------------------------------------
extern "C" void kernel_launch(void* const* d_in, const int* in_sizes, int n_in,
                              void* d_out, int out_size, void* d_ws, size_t ws_size,
                              hipStream_t stream) {
  const float* p3   = (const float*)d_in[0];
  const float* p4   = (const float*)d_in[1];
  const float* p5   = (const float*)d_in[2];
  const float* bbox = (const float*)d_in[3];
  const int*   anc  = (const int*)d_in[4];
  const float* W1   = (const float*)d_in[5];
  const float* b1   = (const float*)d_in[6];
  const float* W2   = (const float*)d_in[7];
  const float* b2   = (const float*)d_in[8];
  const float* Wp   = (const float*)d_in[9];
  const float* bp   = (const float*)d_in[10];
  float* out = (float*)d_out;

  char* ws = (char*)d_ws;
  // Permanent: X [0, 51380224), W1b [51380224, 77070336)
  u16* X   = (u16*)(ws);
  u16* W1b = (u16*)(ws + 51380224);
  // Shared region R at 77070336 (size 44236800; total 121307136 B, proven fit):
  //   Phase A (transpose+roi): t3|t4|t5 fp16 (44040192 B)
  //   Phase B (after roi): W2b|Wpb|H1|H2|{P8 bf16 33554432 / Pf f32 <=16777216}
  char* R = ws + 77070336;
  u16* t3  = (u16*)(R);
  u16* t4  = (u16*)(R + 33554432);
  u16* t5  = (u16*)(R + 41943040);
  u16* W2b = (u16*)(R);
  u16* Wpb = (u16*)(R + 2097152);
  u16* H1  = (u16*)(R + 2293760);
  u16* H2  = (u16*)(R + 6488064);
  u16*   P8 = (u16*)(R + 10682368);   // 8 x 2048x1024 bf16 (FC1 partials)
  float* Pf = (float*)(R + 10682368); // f32 partials for FC2/proj (reuse)
  (void)ws_size; (void)in_sizes; (void)n_in; (void)out_size;

  // Phase A: feats -> channels-last fp16 (feat-only), then ROI + W1 cvt merged
  hipLaunchKernelGGL(transpose_feats, dim3(1344), dim3(256), 0, stream,
                     p3, p4, p5, t3, t4, t5);
  hipLaunchKernelGGL(roi_w1, dim3(3616), dim3(512), 0, stream,
                     t3, t4, t5, bbox, anc, X, W1, W1b);
  // FC1: X @ W1^T — 256² 2-phase pipeline (round-7 exact), uneven split-K=8
  hipLaunchKernelGGL(gemm8_bt, dim3(256), dim3(512), 0, stream,
                     X, 12544, W1b, 12544, P8, 2048, 1024, 8, 4);
  // FC1 reduce + bias + ReLU, merged with W2/Wp cvt (aliases t3: roi is done)
  hipLaunchKernelGGL(reduce_cvt, dim3(3168), dim3(256), 0, stream,
                     P8, b1, H1, W2, Wp, W2b, Wpb);
  // FC2: H1 @ W2^T, split-K=2 (old structure)
  hipLaunchKernelGGL((gemm_bt_splitk<128,128,2,2>), dim3(16, 8, 2), dim3(256), 0, stream,
                     H1, 1024, W2b, 1024, Pf, 2048, 1024, 512);
  hipLaunchKernelGGL((reduce_bias_bf16<2,true>), dim3(8192), dim3(256), 0, stream,
                     Pf, b2, H2, 2048 * 1024, 1023);
  // proj: H2 @ Wp^T (N padded to 96), split-K=8
  hipLaunchKernelGGL((gemm_bt_splitk<128,96,4,1>), dim3(16, 1, 8), dim3(256), 0, stream,
                     H2, 1024, Wpb, 1024, Pf, 2048, 96, 128);
  hipLaunchKernelGGL(reduce_out, dim3(744), dim3(256), 0, stream, Pf, bp, out);
}